// Round 7
// baseline (108.584 us; speedup 1.0000x reference)
//
#include <hip/hip_runtime.h>
#include <hip/hip_bf16.h>

typedef __bf16 bf16x8 __attribute__((ext_vector_type(8)));
typedef float f32x16 __attribute__((ext_vector_type(16)));
typedef unsigned int u32x4 __attribute__((ext_vector_type(4)));
typedef unsigned short u16;

// Problem constants: T=16, N=128, D=512, M=4096, NT=2048, TEMP=0.1
// ws layout: zn bf16[4096*512] (4 MiB) | expsum f32[4096] | possum f32[4096]

// ---------------------------------------------------------------- normalize
// 1024 blocks x 256 threads; one wave per row, full-wave shfl_xor reduce,
// no LDS, no barrier. Also zeroes expsum.
__global__ void nrm_kernel(const float* __restrict__ z, u16* __restrict__ zn,
                           float* __restrict__ expsum) {
    int tid = threadIdx.x;
    int l = tid & 63, w = tid >> 6;
    int row = blockIdx.x * 4 + w;
    const float4* src = (const float4*)(z + row * 512);
    float4 v0 = src[l];
    float4 v1 = src[l + 64];
    float ss = v0.x * v0.x + v0.y * v0.y + v0.z * v0.z + v0.w * v0.w
             + v1.x * v1.x + v1.y * v1.y + v1.z * v1.z + v1.w * v1.w;
#pragma unroll
    for (int off = 32; off; off >>= 1) ss += __shfl_xor(ss, off, 64);
    float sc = 1.0f / fmaxf(sqrtf(ss), 1e-8f);   // matches ref clamp
    __hip_bfloat16 b0[4], b1[4];
    b0[0] = __float2bfloat16(v0.x * sc); b0[1] = __float2bfloat16(v0.y * sc);
    b0[2] = __float2bfloat16(v0.z * sc); b0[3] = __float2bfloat16(v0.w * sc);
    b1[0] = __float2bfloat16(v1.x * sc); b1[1] = __float2bfloat16(v1.y * sc);
    b1[2] = __float2bfloat16(v1.z * sc); b1[3] = __float2bfloat16(v1.w * sc);
    uint2 p0, p1;
    __builtin_memcpy(&p0, b0, 8);
    __builtin_memcpy(&p1, b1, 8);
    ((uint2*)(zn + row * 512))[l] = p0;
    ((uint2*)(zn + row * 512))[l + 64] = p1;
    int gi = blockIdx.x * 256 + tid;
    if (gi < 4096) expsum[gi] = 0.f;
}

// ------------------------------------------- symmetric GEMM (+pos tail)
// Blocks [0,528): triangular (ti<=tj) 128x128 tiles of the symmetric Gram.
//   4 waves/WG, wave owns 32 rows, A (32x512 bf16) resident in 128 VGPRs.
//   STAGING (r5 post-mortem): NO global_load_lds — its scattered per-lane
//   source (32 rows/instr) pinned the kernel at ~47us across r3-r5
//   regardless of conflicts/spill/atomics (warm replays: 1.35MB fetched,
//   same 47us => LDS-DMA scatter pathology, not bandwidth). Reg-staged:
//   coalesced global_load_dwordx4 (8 lanes cover one 128B row-half),
//   ds_write_b128 into a K-MAJOR layout (granule G = (g>>1)*64+(g&1)*32+c
//   for global granule g of col c) so the MFMA-side ds_read_b128 is
//   lane-linear (byte = kc*1024 + l*16) — measured 0 conflicts in r4/r5.
//   Next tile's loads issue BEFORE the MFMA cluster, ds_writes after it
//   (T14 split); one barrier per tile.
//   r6 NaN bug fixed here: prefetch stride is 2048 u32x4 granules
//   (32 rows x 64 granules), NOT 32*128 — r6 read 2x too far (OOB).
//   Column contributions accumulate in registers (colacc[4]), reduced via
//   LDS at kernel end, then 128 atomics/block (r5, verified).
// Blocks [528,656): pos work — 32x32 group Gram, possum[i] = 10*sum dot.
__global__ __launch_bounds__(256, 1) void gemm_kernel(const u16* __restrict__ zn,
                                                      float* __restrict__ expsum,
                                                      float* __restrict__ possum) {
    __shared__ u16 Bt[2][32 * 512];            // 64 KiB double buffer

    int tid = threadIdx.x;
    int wave = tid >> 6;
    int l = tid & 63;
    int m = l & 31, h = l >> 5;

    if (blockIdx.x >= 528) {       // ---------------- positives tail
        if (tid < 64) {
            int g = blockIdx.x - 528;
            int grow = (m < 16) ? (g * 16 + m) : (2048 + g * 16 + (m - 16));
            const u32x4* src = (const u32x4*)(zn + grow * 512);
            f32x16 acc = {};
#pragma unroll
            for (int kc = 0; kc < 32; ++kc) {
                bf16x8 f = __builtin_bit_cast(bf16x8, src[h + 2 * kc]);
                acc = __builtin_amdgcn_mfma_f32_32x32x16_bf16(f, f, acc, 0, 0, 0);
            }
#pragma unroll
            for (int r = 0; r < 16; ++r) {
                int rrow = (r & 3) + 8 * (r >> 2) + 4 * h;
                float v = (rrow == m) ? 0.f : acc[r];
                v += __shfl_xor(v, 1, 64);
                v += __shfl_xor(v, 2, 64);
                v += __shfl_xor(v, 4, 64);
                v += __shfl_xor(v, 8, 64);
                v += __shfl_xor(v, 16, 64);
                if (m == 0) {
                    int gr = (rrow < 16) ? (g * 16 + rrow) : (2048 + g * 16 + (rrow - 16));
                    possum[gr] = v * 10.0f;   // plain store; fin is a separate launch
                }
            }
        }
        return;
    }

    // triangular decode: tile row ti has 32-ti tiles (tj = ti..31)
    int b = blockIdx.x;
    int ti = 0;
    while (b >= 32 - ti) { b -= 32 - ti; ++ti; }
    int tj = ti + b;

    int rowbase = ti * 128 + wave * 32;
    int colbase = tj * 128;
    bool diag = (ti == tj);

    // A fragments, full K=512: row rowbase+m, k-granule h+2*kc
    u32x4 a[32];
    const u32x4* arow = (const u32x4*)(zn + (rowbase + m) * 512);
#pragma unroll
    for (int kc = 0; kc < 32; ++kc) a[kc] = arow[h + 2 * kc];

    float racc[16];
#pragma unroll
    for (int r = 0; r < 16; ++r) racc[r] = 0.f;
    float colacc[4] = {0.f, 0.f, 0.f, 0.f};    // per-lane column partials (static idx)

    // staging geometry: thread (c = tid>>3, g0 = tid&7) owns granules
    // g = g0+8i of col c. Global load: coalesced (8 lanes cover 128B).
    // ds_write K-major: byte = (g>>1)*1024 + (g&1)*512 + c*16
    //                        = wbase + i*4096  (single base + imm offsets).
    int c = tid >> 3, g0 = tid & 7;
    int wbase = (g0 >> 1) * 1024 + (g0 & 1) * 512 + c * 16;
    const u32x4* zsrc = (const u32x4*)(zn + (colbase + c) * 512);

    u32x4 stg[8];
    {   // prologue: stage col-tile 0 into Bt[0]
#pragma unroll
        for (int i = 0; i < 8; ++i) stg[i] = zsrc[g0 + 8 * i];
        char* dst = (char*)Bt[0] + wbase;
#pragma unroll
        for (int i = 0; i < 8; ++i) *(u32x4*)(dst + i * 4096) = stg[i];
    }
    __syncthreads();

#pragma unroll
    for (int ct = 0; ct < 4; ++ct) {
        if (ct < 3) {   // issue next tile's loads early (hide under MFMA)
            // +32 rows = 32*512 u16 = 2048 u32x4 granules (r6 bug: was 4096)
            const u32x4* nsrc = zsrc + (ct + 1) * 2048;
#pragma unroll
            for (int i = 0; i < 8; ++i) stg[i] = nsrc[g0 + 8 * i];
        }
        const char* rb = (const char*)Bt[ct & 1] + l * 16;   // lane-linear base
        f32x16 acc = {};
        __builtin_amdgcn_s_setprio(1);
#pragma unroll
        for (int kc = 0; kc < 32; ++kc) {
            bf16x8 bf = *(const bf16x8*)(rb + kc * 1024);    // conflict-free
            acc = __builtin_amdgcn_mfma_f32_32x32x16_bf16(
                __builtin_bit_cast(bf16x8, a[kc]), bf, acc, 0, 0, 0);
        }
        __builtin_amdgcn_s_setprio(0);

        if (diag && ct == wave) {  // aligned sub-block: mask true diagonal
#pragma unroll
            for (int r = 0; r < 16; ++r) {
                int rrow = (r & 3) + 8 * (r >> 2) + 4 * h;
                if (rrow != m) racc[r] += __builtin_exp2f(acc[r] * 14.426950408889634f);
            }
        } else {
            float csum = 0.f;
#pragma unroll
            for (int r = 0; r < 16; ++r) {
                float e = __builtin_exp2f(acc[r] * 14.426950408889634f);
                racc[r] += e;
                csum += e;
            }
            colacc[ct] += csum;    // register only; no VMEM in the loop
        }

        if (ct < 3) {   // write staged tile into the other buffer
            char* dst = (char*)Bt[(ct + 1) & 1] + wbase;
#pragma unroll
            for (int i = 0; i < 8; ++i) *(u32x4*)(dst + i * 4096) = stg[i];
        }
        __syncthreads();           // staged tile visible; current reads done
    }

    // row sums: reduce over the 32 cols held in lanes of each half
#pragma unroll
    for (int r = 0; r < 16; ++r) {
        float v = racc[r];
        v += __shfl_xor(v, 1, 64);
        v += __shfl_xor(v, 2, 64);
        v += __shfl_xor(v, 4, 64);
        v += __shfl_xor(v, 8, 64);
        v += __shfl_xor(v, 16, 64);
        if (m == 0) {
            int rrow = (r & 3) + 8 * (r >> 2) + 4 * h;
            atomicAdd(&expsum[rowbase + rrow], v);
        }
    }

    // symmetric column sums: cross-wave reduce via LDS (Bt dead after the
    // loop's final barrier), then one atomic per column, end-of-kernel only.
    if (!diag) {
        float* colred = (float*)Bt;            // [4 waves][128 cols]
#pragma unroll
        for (int ct = 0; ct < 4; ++ct) {
            float v = colacc[ct] + __shfl_xor(colacc[ct], 32, 64);  // combine k-halves
            if (h == 0) colred[wave * 128 + ct * 32 + m] = v;
        }
        __syncthreads();
        if (tid < 128) {
            float s = colred[tid] + colred[128 + tid] + colred[256 + tid] + colred[384 + tid];
            atomicAdd(&expsum[colbase + tid], s);
        }
    }
}

// ---------------------------------------------------------------- finalize
__global__ void fin_kernel(const float* __restrict__ expsum,
                           const float* __restrict__ possum, float* __restrict__ out) {
    int tid = threadIdx.x;         // 1024
    float s = 0.f;
    for (int i = tid; i < 4096; i += 1024)
        s += __logf(expsum[i]) - possum[i] * (1.0f / 31.0f);
#pragma unroll
    for (int off = 32; off; off >>= 1) s += __shfl_down(s, off, 64);
    __shared__ float red[16];
    if ((tid & 63) == 0) red[tid >> 6] = s;
    __syncthreads();
    if (tid == 0) {
        float t = 0.f;
#pragma unroll
        for (int i = 0; i < 16; ++i) t += red[i];
        out[0] = t * (1.0f / 4096.0f);
    }
}

extern "C" void kernel_launch(void* const* d_in, const int* in_sizes, int n_in,
                              void* d_out, int out_size, void* d_ws, size_t ws_size,
                              hipStream_t stream) {
    const float* z = (const float*)d_in[0];
    // d_in[1] (done) is provably dead: positive_mask reduces to block-diag + eye.
    u16* zn = (u16*)d_ws;
    float* expsum = (float*)((char*)d_ws + (4u << 20));
    float* possum = expsum + 4096;
    float* out = (float*)d_out;

    nrm_kernel<<<1024, 256, 0, stream>>>(z, zn, expsum);
    gemm_kernel<<<656, 256, 0, stream>>>(zn, expsum, possum);   // 528 sym + 128 pos
    fin_kernel<<<1, 1024, 0, stream>>>(expsum, possum, out);
}